// Round 6
// baseline (50950.674 us; speedup 1.0000x reference)
//
#include <hip/hip_runtime.h>
#include <hip/hip_bf16.h>

#define NPTS 16384
#define KNN 20
#define JC64 8   // knn j-chunks for D=64 kernels
#define JC9 16   // knn j-chunks for D=9 kernel
#define KBUF 10      // per-lane LDS candidate buffer slots
#define KBSTRIDE 11  // u64 stride to spread banks

// ---------------- helpers ----------------

__device__ __forceinline__ void insert20(unsigned long long (&kk)[KNN], unsigned long long key) {
  if (key < kk[KNN - 1]) {
    #pragma unroll
    for (int s = KNN - 1; s >= 1; --s) {
      unsigned long long prev = kk[s - 1];
      kk[s] = (key < prev) ? prev : ((key < kk[s]) ? key : kk[s]);
    }
    kk[0] = (key < kk[0]) ? key : kk[0];
  }
}

__device__ __forceinline__ unsigned ordkey(float d2v) {
  unsigned u = __float_as_uint(d2v);
  return ((int)u < 0) ? ~u : (u | 0x80000000u);   // order-preserving float->uint
}

// ---------------- row squared norms ----------------

template<int D>
__global__ void __launch_bounds__(256) rowsq_kernel(const float* __restrict__ X, float* __restrict__ sq) {
  int n = blockIdx.x * 256 + threadIdx.x;
  float s = 0.f;
  #pragma unroll
  for (int c = 0; c < D; ++c) { float x = X[(size_t)n * D + c]; s = fmaf(x, x, s); }
  sq[n] = s;
}

// ---------------- knn v5 (D=64): lane-pair D-split + 2-cand interleave + ring-buffer selection ----
// Latency model (r5 post-mortem): v1-v3 were ds_read-latency-bound at 2 waves/SIMD with no VGPR
// headroom. v5: qv=32/lane (pair covers 64 dims), 8 ds_read_b128/cand, 2-cand ILP, 4 blocks/CU.

template<int TJ>
__global__ void __launch_bounds__(256, 4) knn5_64_kernel(const float* __restrict__ X,
                                                         const float* __restrict__ sq,
                                                         unsigned long long* __restrict__ part) {
  const int NQB = NPTS / 128;           // 128 query-blocks (128 queries per block)
  int qb = blockIdx.x % NQB;
  int chunk = blockIdx.x / NQB;
  int tid = threadIdx.x;
  int wave = tid >> 6, lane = tid & 63;
  int half = lane >> 5, qi = lane & 31;
  int q = qb * 128 + wave * 32 + qi;

  __shared__ float Xs[TJ * 64];
  __shared__ float sqs[TJ];
  __shared__ unsigned long long buf[256 * KBSTRIDE];

  float qv[32];
  {
    const float4* qp = reinterpret_cast<const float4*>(&X[(size_t)q * 64 + half * 32]);
    #pragma unroll
    for (int c4 = 0; c4 < 8; ++c4) {
      float4 v = qp[c4];
      qv[c4 * 4 + 0] = v.x; qv[c4 * 4 + 1] = v.y; qv[c4 * 4 + 2] = v.z; qv[c4 * 4 + 3] = v.w;
    }
  }
  float sqq = sq[q];

  unsigned long long kk[KNN];
  #pragma unroll
  for (int s = 0; s < KNN; ++s) kk[s] = ~0ull;
  unsigned utau = 0xFFFFFFFFu;
  int cnt = 0;
  const int bbase = tid * KBSTRIDE;

  const int CH = NPTS / JC64;           // 2048
  const int j0 = chunk * CH;
  for (int jt = j0; jt < j0 + CH; jt += TJ) {
    __syncthreads();
    {
      float4* Xs4 = reinterpret_cast<float4*>(Xs);
      const float4* X4 = reinterpret_cast<const float4*>(X) + (size_t)jt * 16;
      #pragma unroll
      for (int i = 0; i < TJ * 16 / 256; ++i) Xs4[tid + i * 256] = X4[tid + i * 256];
    }
    if (tid < TJ) sqs[tid] = sq[jt + tid];
    __syncthreads();

    for (int jj = 0; jj < TJ; jj += 2) {
      const float4* ra = reinterpret_cast<const float4*>(&Xs[jj * 64 + half * 32]);
      const float4* rb = reinterpret_cast<const float4*>(&Xs[(jj + 1) * 64 + half * 32]);
      float a0 = 0.f, a1 = 0.f, a2 = 0.f, a3 = 0.f;
      float b0 = 0.f, b1 = 0.f, b2 = 0.f, b3 = 0.f;
      #pragma unroll
      for (int c4 = 0; c4 < 8; c4 += 2) {
        float4 xa0 = ra[c4], xa1 = ra[c4 + 1];
        float4 xb0 = rb[c4], xb1 = rb[c4 + 1];
        a0 = fmaf(qv[c4 * 4 + 0], xa0.x, a0); a1 = fmaf(qv[c4 * 4 + 1], xa0.y, a1);
        a2 = fmaf(qv[c4 * 4 + 2], xa0.z, a2); a3 = fmaf(qv[c4 * 4 + 3], xa0.w, a3);
        b0 = fmaf(qv[c4 * 4 + 0], xb0.x, b0); b1 = fmaf(qv[c4 * 4 + 1], xb0.y, b1);
        b2 = fmaf(qv[c4 * 4 + 2], xb0.z, b2); b3 = fmaf(qv[c4 * 4 + 3], xb0.w, b3);
        a0 = fmaf(qv[c4 * 4 + 4], xa1.x, a0); a1 = fmaf(qv[c4 * 4 + 5], xa1.y, a1);
        a2 = fmaf(qv[c4 * 4 + 6], xa1.z, a2); a3 = fmaf(qv[c4 * 4 + 7], xa1.w, a3);
        b0 = fmaf(qv[c4 * 4 + 4], xb1.x, b0); b1 = fmaf(qv[c4 * 4 + 5], xb1.y, b1);
        b2 = fmaf(qv[c4 * 4 + 6], xb1.z, b2); b3 = fmaf(qv[c4 * 4 + 7], xb1.w, b3);
      }
      float dota = (a0 + a1) + (a2 + a3);
      float dotb = (b0 + b1) + (b2 + b3);
      dota += __shfl_xor(dota, 32);     // pair lanes hold identical full dot (fp add commutative)
      dotb += __shfl_xor(dotb, 32);
      float d2a = (sqq + sqs[jj]) - 2.f * dota;
      float d2b = (sqq + sqs[jj + 1]) - 2.f * dotb;

      int t = (jt - j0) + jj;
      unsigned ua = ordkey(d2a), ub = ordkey(d2b);
      unsigned long long ka = ((unsigned long long)ua << 14) | (unsigned)(jt + jj);
      unsigned long long kb = ((unsigned long long)ub << 14) | (unsigned)(jt + jj + 1);
      if (t < 128) {                    // fill: wave-uniform direct insert
        insert20(kk, ka);
        insert20(kk, kb);
        utau = (unsigned)(kk[KNN - 1] >> 14);
      } else {
        if (ua <= utau) {
          buf[bbase + cnt] = ka; ++cnt;
          if (cnt == KBUF) {
            #pragma unroll
            for (int i = 0; i < KBUF; ++i) insert20(kk, buf[bbase + i]);
            cnt = 0; utau = (unsigned)(kk[KNN - 1] >> 14);
          }
        }
        if (ub <= utau) {
          buf[bbase + cnt] = kb; ++cnt;
          if (cnt == KBUF) {
            #pragma unroll
            for (int i = 0; i < KBUF; ++i) insert20(kk, buf[bbase + i]);
            cnt = 0; utau = (unsigned)(kk[KNN - 1] >> 14);
          }
        }
      }
    }

    // deterministic wave-uniform flush at tile boundary
    #pragma unroll
    for (int i = 0; i < KBUF; ++i) {
      unsigned long long v = (i < cnt) ? buf[bbase + i] : ~0ull;
      insert20(kk, v);
    }
    cnt = 0;
    utau = (unsigned)(kk[KNN - 1] >> 14);
  }

  if (half == 0) {
    unsigned long long* o = part + ((size_t)chunk * NPTS + q) * KNN;
    #pragma unroll
    for (int s = 0; s < KNN; ++s) o[s] = kk[s];
  }
}

// ---------------- knn v5 (D=9): stride-12 padded LDS rows (3x b128 reads), ring-buffer selection --

template<int TJ>
__global__ void __launch_bounds__(256, 4) knn5_9_kernel(const float* __restrict__ X,
                                                        const float* __restrict__ sq,
                                                        unsigned long long* __restrict__ part) {
  const int NQB = NPTS / 256;           // 64
  int qb = blockIdx.x % NQB;
  int chunk = blockIdx.x / NQB;
  int tid = threadIdx.x;
  int q = qb * 256 + tid;

  __shared__ float Xs[TJ * 12];
  __shared__ float sqs[TJ];
  __shared__ unsigned long long buf[256 * KBSTRIDE];

  float qv[9];
  #pragma unroll
  for (int c = 0; c < 9; ++c) qv[c] = X[(size_t)q * 9 + c];
  float sqq = sq[q];

  unsigned long long kk[KNN];
  #pragma unroll
  for (int s = 0; s < KNN; ++s) kk[s] = ~0ull;
  unsigned utau = 0xFFFFFFFFu;
  int cnt = 0;
  const int bbase = tid * KBSTRIDE;

  const int CH = NPTS / JC9;            // 1024
  const int j0 = chunk * CH;
  for (int jt = j0; jt < j0 + CH; jt += TJ) {
    __syncthreads();
    for (int i = tid; i < TJ * 9; i += 256) {
      int row = i / 9, col = i - row * 9;
      Xs[row * 12 + col] = X[(size_t)jt * 9 + i];
    }
    if (tid < TJ) sqs[tid] = sq[jt + tid];
    __syncthreads();

    for (int jj = 0; jj < TJ; jj += 2) {
      const float4* ra = reinterpret_cast<const float4*>(&Xs[jj * 12]);
      const float4* rb = reinterpret_cast<const float4*>(&Xs[(jj + 1) * 12]);
      float4 xa0 = ra[0], xa1 = ra[1], xa2 = ra[2];
      float4 xb0 = rb[0], xb1 = rb[1], xb2 = rb[2];
      float a0 = qv[0] * xa0.x, a1 = qv[1] * xa0.y, a2 = qv[2] * xa0.z;
      a0 = fmaf(qv[3], xa0.w, a0); a1 = fmaf(qv[4], xa1.x, a1); a2 = fmaf(qv[5], xa1.y, a2);
      a0 = fmaf(qv[6], xa1.z, a0); a1 = fmaf(qv[7], xa1.w, a1); a2 = fmaf(qv[8], xa2.x, a2);
      float b0 = qv[0] * xb0.x, b1 = qv[1] * xb0.y, b2 = qv[2] * xb0.z;
      b0 = fmaf(qv[3], xb0.w, b0); b1 = fmaf(qv[4], xb1.x, b1); b2 = fmaf(qv[5], xb1.y, b2);
      b0 = fmaf(qv[6], xb1.z, b0); b1 = fmaf(qv[7], xb1.w, b1); b2 = fmaf(qv[8], xb2.x, b2);
      float d2a = (sqq + sqs[jj]) - 2.f * ((a0 + a1) + a2);
      float d2b = (sqq + sqs[jj + 1]) - 2.f * ((b0 + b1) + b2);

      int t = (jt - j0) + jj;
      unsigned ua = ordkey(d2a), ub = ordkey(d2b);
      unsigned long long ka = ((unsigned long long)ua << 14) | (unsigned)(jt + jj);
      unsigned long long kb = ((unsigned long long)ub << 14) | (unsigned)(jt + jj + 1);
      if (t < 128) {
        insert20(kk, ka);
        insert20(kk, kb);
        utau = (unsigned)(kk[KNN - 1] >> 14);
      } else {
        if (ua <= utau) {
          buf[bbase + cnt] = ka; ++cnt;
          if (cnt == KBUF) {
            #pragma unroll
            for (int i = 0; i < KBUF; ++i) insert20(kk, buf[bbase + i]);
            cnt = 0; utau = (unsigned)(kk[KNN - 1] >> 14);
          }
        }
        if (ub <= utau) {
          buf[bbase + cnt] = kb; ++cnt;
          if (cnt == KBUF) {
            #pragma unroll
            for (int i = 0; i < KBUF; ++i) insert20(kk, buf[bbase + i]);
            cnt = 0; utau = (unsigned)(kk[KNN - 1] >> 14);
          }
        }
      }
    }

    #pragma unroll
    for (int i = 0; i < KBUF; ++i) {
      unsigned long long v = (i < cnt) ? buf[bbase + i] : ~0ull;
      insert20(kk, v);
    }
    cnt = 0;
    utau = (unsigned)(kk[KNN - 1] >> 14);
  }

  unsigned long long* o = part + ((size_t)chunk * NPTS + q) * KNN;
  #pragma unroll
  for (int s = 0; s < KNN; ++s) o[s] = kk[s];
}

// ---------------- merge NL sorted partial lists -> top-20 indices ----------------

template<int NL>
__global__ void __launch_bounds__(256) merge_kernel(const unsigned long long* __restrict__ part,
                                                    int* __restrict__ idx) {
  int q = blockIdx.x * 256 + threadIdx.x;
  int cur[NL];
  #pragma unroll
  for (int l = 0; l < NL; ++l) cur[l] = 0;
  for (int r = 0; r < KNN; ++r) {
    unsigned long long best = ~0ull; int bl = 0;
    #pragma unroll
    for (int l = 0; l < NL; ++l) {
      unsigned long long v = part[((size_t)l * NPTS + q) * KNN + cur[l]];
      if (v < best) { best = v; bl = l; }
    }
    idx[q * KNN + r] = (int)(best & 0x3FFFu);
    #pragma unroll
    for (int l = 0; l < NL; ++l) cur[l] += (l == bl) ? 1 : 0;
  }
}

// ---------------- per-point linear: Y = A[N,K] @ W[K,64] + b ----------------

template<int K>
__global__ void __launch_bounds__(256) linear_kernel(const float* __restrict__ A,
                                                     const float* __restrict__ W,
                                                     const float* __restrict__ b,
                                                     float* __restrict__ Y) {
  int t = threadIdx.x;
  int n = blockIdx.x * 4 + (t >> 6);
  int o = t & 63;
  float acc = b[o];
  #pragma unroll
  for (int k = 0; k < K; ++k) acc = fmaf(A[(size_t)n * K + k], W[k * 64 + o], acc);
  Y[(size_t)n * 64 + o] = acc;
}

// ---------------- gather neighbors + max over k ----------------

__global__ void __launch_bounds__(256) gathermax_kernel(const float* __restrict__ Y,
                                                        const int* __restrict__ idx,
                                                        float* __restrict__ Xo) {
  int t = threadIdx.x;
  int n = blockIdx.x * 4 + (t >> 6);
  int c = t & 63;
  const int* row = idx + n * KNN;
  float m = -INFINITY;
  #pragma unroll
  for (int k = 0; k < KNN; ++k) m = fmaxf(m, Y[(size_t)row[k] * 64 + c]);
  Xo[(size_t)n * 64 + c] = m;
}

// ---------------- pairwise max pool over concat [X1|X2|X3] ----------------

__global__ void __launch_bounds__(256) pairmax_kernel(const float* __restrict__ X1,
                                                      const float* __restrict__ X2,
                                                      const float* __restrict__ X3,
                                                      float* __restrict__ P) {
  int i = blockIdx.x * 256 + threadIdx.x;   // over NPTS*96
  int n = i / 96, c = i % 96;
  const float* src = (c < 32) ? X1 : ((c < 64) ? X2 : X3);
  int cc = (c & 31) * 2;
  P[i] = fmaxf(src[(size_t)n * 64 + cc], src[(size_t)n * 64 + cc + 1]);
}

// ---------------- fp32 tiled GEMM: C[N,Nc] = A[N,K] @ B[K,Nc] + bias ----------------

template<bool RELU>
__global__ void __launch_bounds__(256) gemm_kernel(const float* __restrict__ A,
                                                   const float* __restrict__ B,
                                                   const float* __restrict__ bias,
                                                   float* __restrict__ C,
                                                   int K, int Nc) {
  __shared__ float As[16][68];
  __shared__ float Bs[16][68];
  int tid = threadIdx.x;
  int m0 = blockIdx.x * 64, n0 = blockIdx.y * 64;
  int tx = tid & 15, ty = tid >> 4;
  int ar = tid >> 2, ak = (tid & 3) * 4;
  int bk = tid >> 4, bn = (tid & 15) * 4;
  float acc[4][4] = {};
  for (int kt = 0; kt < K; kt += 16) {
    float4 a4 = *reinterpret_cast<const float4*>(&A[(size_t)(m0 + ar) * K + kt + ak]);
    float4 b4 = *reinterpret_cast<const float4*>(&B[(size_t)(kt + bk) * Nc + n0 + bn]);
    __syncthreads();
    As[ak + 0][ar] = a4.x; As[ak + 1][ar] = a4.y; As[ak + 2][ar] = a4.z; As[ak + 3][ar] = a4.w;
    *reinterpret_cast<float4*>(&Bs[bk][bn]) = b4;
    __syncthreads();
    #pragma unroll
    for (int kx = 0; kx < 16; ++kx) {
      float4 av = *reinterpret_cast<const float4*>(&As[kx][ty * 4]);
      float4 bv = *reinterpret_cast<const float4*>(&Bs[kx][tx * 4]);
      float a_[4] = {av.x, av.y, av.z, av.w};
      float b_[4] = {bv.x, bv.y, bv.z, bv.w};
      #pragma unroll
      for (int i = 0; i < 4; ++i)
        #pragma unroll
        for (int j = 0; j < 4; ++j)
          acc[i][j] = fmaf(a_[i], b_[j], acc[i][j]);
    }
  }
  #pragma unroll
  for (int i = 0; i < 4; ++i) {
    int m = m0 + ty * 4 + i;
    float4 r;
    r.x = acc[i][0] + bias[n0 + tx * 4 + 0];
    r.y = acc[i][1] + bias[n0 + tx * 4 + 1];
    r.z = acc[i][2] + bias[n0 + tx * 4 + 2];
    r.w = acc[i][3] + bias[n0 + tx * 4 + 3];
    if (RELU) { r.x = fmaxf(r.x, 0.f); r.y = fmaxf(r.y, 0.f); r.z = fmaxf(r.z, 0.f); r.w = fmaxf(r.w, 0.f); }
    *reinterpret_cast<float4*>(&C[(size_t)m * Nc + n0 + tx * 4]) = r;
  }
}

// ---------------- concat-A GEMM: A = [X1|X2|X3|H], K=1216 ----------------

template<bool RELU>
__global__ void __launch_bounds__(256) gemm_cat_kernel(const float* __restrict__ X1,
                                                       const float* __restrict__ X2,
                                                       const float* __restrict__ X3,
                                                       const float* __restrict__ H,
                                                       const float* __restrict__ B,
                                                       const float* __restrict__ bias,
                                                       float* __restrict__ C, int Nc) {
  const int K = 1216;
  __shared__ float As[16][68];
  __shared__ float Bs[16][68];
  int tid = threadIdx.x;
  int m0 = blockIdx.x * 64, n0 = blockIdx.y * 64;
  int tx = tid & 15, ty = tid >> 4;
  int ar = tid >> 2, ak = (tid & 3) * 4;
  int bk = tid >> 4, bn = (tid & 15) * 4;
  float acc[4][4] = {};
  for (int kt = 0; kt < K; kt += 16) {
    const float* src; int ld, ko;
    if (kt < 64)       { src = X1; ld = 64;   ko = kt; }
    else if (kt < 128) { src = X2; ld = 64;   ko = kt - 64; }
    else if (kt < 192) { src = X3; ld = 64;   ko = kt - 128; }
    else               { src = H;  ld = 1024; ko = kt - 192; }
    float4 a4 = *reinterpret_cast<const float4*>(&src[(size_t)(m0 + ar) * ld + ko + ak]);
    float4 b4 = *reinterpret_cast<const float4*>(&B[(size_t)(kt + bk) * Nc + n0 + bn]);
    __syncthreads();
    As[ak + 0][ar] = a4.x; As[ak + 1][ar] = a4.y; As[ak + 2][ar] = a4.z; As[ak + 3][ar] = a4.w;
    *reinterpret_cast<float4*>(&Bs[bk][bn]) = b4;
    __syncthreads();
    #pragma unroll
    for (int kx = 0; kx < 16; ++kx) {
      float4 av = *reinterpret_cast<const float4*>(&As[kx][ty * 4]);
      float4 bv = *reinterpret_cast<const float4*>(&Bs[kx][tx * 4]);
      float a_[4] = {av.x, av.y, av.z, av.w};
      float b_[4] = {bv.x, bv.y, bv.z, bv.w};
      #pragma unroll
      for (int i = 0; i < 4; ++i)
        #pragma unroll
        for (int j = 0; j < 4; ++j)
          acc[i][j] = fmaf(a_[i], b_[j], acc[i][j]);
    }
  }
  #pragma unroll
  for (int i = 0; i < 4; ++i) {
    int m = m0 + ty * 4 + i;
    float4 r;
    r.x = acc[i][0] + bias[n0 + tx * 4 + 0];
    r.y = acc[i][1] + bias[n0 + tx * 4 + 1];
    r.z = acc[i][2] + bias[n0 + tx * 4 + 2];
    r.w = acc[i][3] + bias[n0 + tx * 4 + 3];
    if (RELU) { r.x = fmaxf(r.x, 0.f); r.y = fmaxf(r.y, 0.f); r.z = fmaxf(r.z, 0.f); r.w = fmaxf(r.w, 0.f); }
    *reinterpret_cast<float4*>(&C[(size_t)m * Nc + n0 + tx * 4]) = r;
  }
}

// ---------------- final [128 -> 3] ----------------

__global__ void __launch_bounds__(256) final3_kernel(const float* __restrict__ Z,
                                                     const float* __restrict__ W,
                                                     const float* __restrict__ b,
                                                     float* __restrict__ out) {
  int n = blockIdx.x * 256 + threadIdx.x;
  float a0 = b[0], a1 = b[1], a2 = b[2];
  #pragma unroll 4
  for (int k = 0; k < 128; ++k) {
    float z = Z[(size_t)n * 128 + k];
    a0 = fmaf(z, W[k * 3 + 0], a0);
    a1 = fmaf(z, W[k * 3 + 1], a1);
    a2 = fmaf(z, W[k * 3 + 2], a2);
  }
  out[n * 3 + 0] = a0;
  out[n * 3 + 1] = a1;
  out[n * 3 + 2] = a2;
}

// ---------------- launch ----------------

extern "C" void kernel_launch(void* const* d_in, const int* in_sizes, int n_in,
                              void* d_out, int out_size, void* d_ws, size_t ws_size,
                              hipStream_t stream) {
  const float* X   = (const float*)d_in[0];
  const float* w1  = (const float*)d_in[1];
  const float* b1  = (const float*)d_in[2];
  const float* w2  = (const float*)d_in[3];
  const float* b2  = (const float*)d_in[4];
  const float* w3  = (const float*)d_in[5];
  const float* b3  = (const float*)d_in[6];
  const float* wc1 = (const float*)d_in[7];
  const float* bc1 = (const float*)d_in[8];
  const float* wc2 = (const float*)d_in[9];
  const float* bc2 = (const float*)d_in[10];
  const float* wc3 = (const float*)d_in[11];
  const float* bc3 = (const float*)d_in[12];
  const float* wc4 = (const float*)d_in[13];
  const float* bc4 = (const float*)d_in[14];
  float* out = (float*)d_out;

  char* ws = (char*)d_ws;
  size_t off = 0;
  auto alloc = [&](size_t bytes) -> void* {
    void* p = ws + off;
    off += (bytes + 255) & ~(size_t)255;
    return p;
  };
  float* sqb = (float*)alloc((size_t)NPTS * 4);
  float* Y   = (float*)alloc((size_t)NPTS * 64 * 4);
  float* X1  = (float*)alloc((size_t)NPTS * 64 * 4);
  float* X2  = (float*)alloc((size_t)NPTS * 64 * 4);
  float* X3  = (float*)alloc((size_t)NPTS * 64 * 4);
  float* Hb  = (float*)alloc((size_t)NPTS * 1024 * 4);          // 67 MB
  unsigned long long* part = (unsigned long long*)Hb;           // aliases H (dead before H written): <=42 MB
  float* Z1  = (float*)alloc((size_t)NPTS * 256 * 4);           // 16.8 MB
  int*   idx = (int*)Z1;                                        // aliases Z1 (dead before Z1 written)
  float* Z2  = (float*)alloc((size_t)NPTS * 256 * 4);
  float* P   = (float*)Z2;                                      // aliases Z2 (dead before Z2 written)
  float* Z3  = (float*)alloc((size_t)NPTS * 128 * 4);
  (void)ws_size; (void)in_sizes; (void)n_in; (void)out_size;

  dim3 b256(256);

  // Block 1 (D=9)
  rowsq_kernel<9><<<NPTS / 256, b256, 0, stream>>>(X, sqb);
  knn5_9_kernel<64><<<(NPTS / 256) * JC9, b256, 0, stream>>>(X, sqb, part);
  merge_kernel<JC9><<<NPTS / 256, b256, 0, stream>>>(part, idx);
  linear_kernel<9><<<NPTS / 4, b256, 0, stream>>>(X, w1, b1, Y);
  gathermax_kernel<<<NPTS / 4, b256, 0, stream>>>(Y, idx, X1);

  // Block 2 (D=64)
  rowsq_kernel<64><<<NPTS / 256, b256, 0, stream>>>(X1, sqb);
  knn5_64_kernel<64><<<(NPTS / 128) * JC64, b256, 0, stream>>>(X1, sqb, part);
  merge_kernel<JC64><<<NPTS / 256, b256, 0, stream>>>(part, idx);
  linear_kernel<64><<<NPTS / 4, b256, 0, stream>>>(X1, w2, b2, Y);
  gathermax_kernel<<<NPTS / 4, b256, 0, stream>>>(Y, idx, X2);

  // Block 3 (D=64)
  rowsq_kernel<64><<<NPTS / 256, b256, 0, stream>>>(X2, sqb);
  knn5_64_kernel<64><<<(NPTS / 128) * JC64, b256, 0, stream>>>(X2, sqb, part);
  merge_kernel<JC64><<<NPTS / 256, b256, 0, stream>>>(part, idx);
  linear_kernel<64><<<NPTS / 4, b256, 0, stream>>>(X2, w2, b2, Y);
  gathermax_kernel<<<NPTS / 4, b256, 0, stream>>>(Y, idx, X3);

  // Head
  pairmax_kernel<<<(NPTS * 96) / 256, b256, 0, stream>>>(X1, X2, X3, P);
  gemm_kernel<false><<<dim3(NPTS / 64, 1024 / 64), b256, 0, stream>>>(P, w3, b3, Hb, 96, 1024);
  gemm_cat_kernel<true><<<dim3(NPTS / 64, 256 / 64), b256, 0, stream>>>(X1, X2, X3, Hb, wc1, bc1, Z1, 256);
  gemm_kernel<true><<<dim3(NPTS / 64, 256 / 64), b256, 0, stream>>>(Z1, wc2, bc2, Z2, 256, 256);
  gemm_kernel<true><<<dim3(NPTS / 64, 128 / 64), b256, 0, stream>>>(Z2, wc3, bc3, Z3, 256, 128);
  final3_kernel<<<NPTS / 256, b256, 0, stream>>>(Z3, wc4, bc4, out);
}

// Round 7
// 3527.671 us; speedup vs baseline: 14.4431x; 14.4431x over previous
//
#include <hip/hip_runtime.h>
#include <hip/hip_bf16.h>

#define NPTS 16384
#define KNN 20
#define JC64 2   // candidate chunks for D=64 knn
#define JC9 4    // candidate chunks for D=9 knn
#define QCAP 24  // per-query LDS candidate buffer slots

// ---------------- helpers ----------------

__device__ __forceinline__ void insert20(unsigned long long (&kk)[KNN], unsigned long long key) {
  if (key < kk[KNN - 1]) {
    #pragma unroll
    for (int s = KNN - 1; s >= 1; --s) {
      unsigned long long prev = kk[s - 1];
      kk[s] = (key < prev) ? prev : ((key < kk[s]) ? key : kk[s]);
    }
    kk[0] = (key < kk[0]) ? key : kk[0];
  }
}

__device__ __forceinline__ unsigned ordkey(float d2v) {
  unsigned u = __float_as_uint(d2v);
  return ((int)u < 0) ? ~u : (u | 0x80000000u);   // order-preserving float->uint
}

// ---------------- row squared norms ----------------

template<int D>
__global__ void __launch_bounds__(256) rowsq_kernel(const float* __restrict__ X, float* __restrict__ sq) {
  int n = blockIdx.x * 256 + threadIdx.x;
  float s = 0.f;
  #pragma unroll
  for (int c = 0; c < D; ++c) { float x = X[(size_t)n * D + c]; s = fmaf(x, x, s); }
  sq[n] = s;
}

// ---------------- knn v6: GEMM-tiled distances + fused exact top-20 ----------------
// r1-r5 lesson: broadcast LDS reads (16 b128 per candidate per wave for 64 FMA) are the
// bottleneck, invariant to selection scheme. v6 register-tiles d2 like a GEMM (4x8 acc,
// 3 b128 per 32 FMA) and fuses exact selection: per-query top-20 lists + tau in LDS,
// threshold-filtered pushes to per-query buffers, per-tile batched merges, overflow-retry
// loop (handles the tile-0 flood; correctness independent of buffer capacity).
// NOTE: no launch_bounds occupancy cap (r6: (256,4) capped VGPR->64 and spilled 100GB).

template<int KD, int JC, int TILES>
__global__ void __launch_bounds__(256) knn6_kernel(const float* __restrict__ X,
                                                   const float* __restrict__ sq,
                                                   unsigned long long* __restrict__ part) {
  const int NQB = NPTS / 64;            // 256 query-blocks
  const int qb = blockIdx.x % NQB;
  const int chunk = blockIdx.x / NQB;
  const int tid = threadIdx.x;
  const int tx = tid & 15, ty = tid >> 4;   // n = tx*8+j (j<8), m = ty*4+i (i<4)
  const int m0 = qb * 64;

  __shared__ float Qs[KD * 68];             // [k][m], stride 68 (16B-aligned b128 reads)
  __shared__ float Cs[KD * 132];            // [k][n], stride 132
  __shared__ float sqq_s[64];
  __shared__ float sqc_s[128];
  __shared__ unsigned long long lists[64 * 21];  // sorted top-20 per query (+pad)
  __shared__ unsigned long long qbuf[64 * QCAP];
  __shared__ int qcnt[64];
  __shared__ int sflag[2];

  // ---- init lists / counters / sqq ----
  if (tid < 64) {
    sqq_s[tid] = sq[m0 + tid];
    qcnt[tid] = 0;
    #pragma unroll
    for (int s = 0; s < KNN; ++s) lists[tid * 21 + s] = ~0ull;
  }
  if (tid < 2) sflag[tid] = 0;

  // ---- stage Q tile (once per block), transposed to [k][m] ----
  if constexpr (KD == 64) {
    for (int c = tid; c < 1024; c += 256) {
      int k4 = c & 15, m = c >> 4;          // 16 lanes read one row contiguously (coalesced)
      float4 v = *reinterpret_cast<const float4*>(&X[(size_t)(m0 + m) * 64 + k4 * 4]);
      Qs[(k4 * 4 + 0) * 68 + m] = v.x; Qs[(k4 * 4 + 1) * 68 + m] = v.y;
      Qs[(k4 * 4 + 2) * 68 + m] = v.z; Qs[(k4 * 4 + 3) * 68 + m] = v.w;
    }
  } else {
    for (int i = tid; i < 64 * KD; i += 256) {
      int m = i / KD, k = i - m * KD;
      Qs[k * 68 + m] = X[(size_t)(m0 + m) * KD + k];
    }
  }
  __syncthreads();

  float sqq_r[4];
  #pragma unroll
  for (int i = 0; i < 4; ++i) sqq_r[i] = sqq_s[ty * 4 + i];

  const int CH = NPTS / JC;
  const int j0 = chunk * CH;

  for (int tile = 0; tile < TILES; ++tile) {
    const int jt = j0 + tile * 128;

    // ---- stage C tile [k][n] + sqc ----
    if constexpr (KD == 64) {
      for (int c = tid; c < 2048; c += 256) {
        int k4 = c & 15, n = c >> 4;
        float4 v = *reinterpret_cast<const float4*>(&X[(size_t)(jt + n) * 64 + k4 * 4]);
        Cs[(k4 * 4 + 0) * 132 + n] = v.x; Cs[(k4 * 4 + 1) * 132 + n] = v.y;
        Cs[(k4 * 4 + 2) * 132 + n] = v.z; Cs[(k4 * 4 + 3) * 132 + n] = v.w;
      }
    } else {
      for (int i = tid; i < 128 * KD; i += 256) {
        int n = i / KD, k = i - n * KD;
        Cs[k * 132 + n] = X[(size_t)(jt + n) * KD + k];
      }
    }
    if (tid < 128) sqc_s[tid] = sq[jt + tid];
    __syncthreads();

    // ---- GEMM: acc[4][8] = Q[m]·C[n] over K=KD ----
    float acc[4][8];
    #pragma unroll
    for (int i = 0; i < 4; ++i)
      #pragma unroll
      for (int j = 0; j < 8; ++j) acc[i][j] = 0.f;

    #pragma unroll 8
    for (int k = 0; k < KD; ++k) {
      float4 a  = *reinterpret_cast<const float4*>(&Qs[k * 68 + ty * 4]);
      float4 c0 = *reinterpret_cast<const float4*>(&Cs[k * 132 + tx * 8]);
      float4 c1 = *reinterpret_cast<const float4*>(&Cs[k * 132 + tx * 8 + 4]);
      float av[4] = {a.x, a.y, a.z, a.w};
      float cv[8] = {c0.x, c0.y, c0.z, c0.w, c1.x, c1.y, c1.z, c1.w};
      #pragma unroll
      for (int i = 0; i < 4; ++i)
        #pragma unroll
        for (int j = 0; j < 8; ++j)
          acc[i][j] = fmaf(av[i], cv[j], acc[i][j]);
    }

    // ---- fused selection epilogue ----
    float sqc_r[8];
    #pragma unroll
    for (int j = 0; j < 8; ++j) sqc_r[j] = sqc_s[tx * 8 + j];

    unsigned mask = 0;                      // bit set = key resolved (stored or rejected)
    int r = 0;
    while (true) {
      // push phase: filter vs stale tau (over-admits only -> exact)
      #pragma unroll
      for (int i = 0; i < 4; ++i) {
        int m = ty * 4 + i;
        unsigned tauhi = (unsigned)(lists[m * 21 + 19] >> 14);
        #pragma unroll
        for (int j = 0; j < 8; ++j) {
          int bit = i * 8 + j;
          if (mask & (1u << bit)) continue;
          float d2v = (sqq_r[i] + sqc_r[j]) - 2.f * acc[i][j];
          unsigned u = ordkey(d2v);
          if (u <= tauhi) {
            int idx = atomicAdd(&qcnt[m], 1);
            if (idx < QCAP) {
              qbuf[m * QCAP + idx] =
                  ((unsigned long long)u << 14) | (unsigned)(jt + tx * 8 + j);
              mask |= 1u << bit;
            }
            // idx >= QCAP: overflow, retry next round with tightened tau
          } else mask |= 1u << bit;
        }
      }
      __syncthreads();
      // merge phase: one thread per query, spread across all 4 waves
      if ((tid & 3) == 0) {
        int m = tid >> 2;
        int cnt = qcnt[m];
        if (cnt > 0) {
          if (cnt > QCAP) { sflag[r & 1] = 1; cnt = QCAP; }
          unsigned long long kk[KNN];
          #pragma unroll
          for (int s = 0; s < KNN; ++s) kk[s] = lists[m * 21 + s];
          for (int t = 0; t < cnt; ++t) insert20(kk, qbuf[m * QCAP + t]);
          #pragma unroll
          for (int s = 0; s < KNN; ++s) lists[m * 21 + s] = kk[s];
          qcnt[m] = 0;
        }
      }
      if (tid == 1) sflag[(r + 1) & 1] = 0;   // pre-clear next round's flag slot
      __syncthreads();
      if (sflag[r & 1] == 0) break;           // uniform: all stored keys merged, none lost
      ++r;
    }
  }

  // ---- write out sorted partial lists ----
  if ((tid & 3) == 0) {
    int m = tid >> 2;
    unsigned long long* o = part + ((size_t)chunk * NPTS + (m0 + m)) * KNN;
    #pragma unroll
    for (int s = 0; s < KNN; ++s) o[s] = lists[m * 21 + s];
  }
}

// ---------------- merge NL sorted partial lists -> top-20 indices ----------------

template<int NL>
__global__ void __launch_bounds__(256) merge_kernel(const unsigned long long* __restrict__ part,
                                                    int* __restrict__ idx) {
  int q = blockIdx.x * 256 + threadIdx.x;
  int cur[NL];
  #pragma unroll
  for (int l = 0; l < NL; ++l) cur[l] = 0;
  for (int r = 0; r < KNN; ++r) {
    unsigned long long best = ~0ull; int bl = 0;
    #pragma unroll
    for (int l = 0; l < NL; ++l) {
      unsigned long long v = part[((size_t)l * NPTS + q) * KNN + cur[l]];
      if (v < best) { best = v; bl = l; }
    }
    idx[q * KNN + r] = (int)(best & 0x3FFFu);
    #pragma unroll
    for (int l = 0; l < NL; ++l) cur[l] += (l == bl) ? 1 : 0;
  }
}

// ---------------- per-point linear: Y = A[N,K] @ W[K,64] + b ----------------

template<int K>
__global__ void __launch_bounds__(256) linear_kernel(const float* __restrict__ A,
                                                     const float* __restrict__ W,
                                                     const float* __restrict__ b,
                                                     float* __restrict__ Y) {
  int t = threadIdx.x;
  int n = blockIdx.x * 4 + (t >> 6);
  int o = t & 63;
  float acc = b[o];
  #pragma unroll
  for (int k = 0; k < K; ++k) acc = fmaf(A[(size_t)n * K + k], W[k * 64 + o], acc);
  Y[(size_t)n * 64 + o] = acc;
}

// ---------------- gather neighbors + max over k ----------------

__global__ void __launch_bounds__(256) gathermax_kernel(const float* __restrict__ Y,
                                                        const int* __restrict__ idx,
                                                        float* __restrict__ Xo) {
  int t = threadIdx.x;
  int n = blockIdx.x * 4 + (t >> 6);
  int c = t & 63;
  const int* row = idx + n * KNN;
  float m = -INFINITY;
  #pragma unroll
  for (int k = 0; k < KNN; ++k) m = fmaxf(m, Y[(size_t)row[k] * 64 + c]);
  Xo[(size_t)n * 64 + c] = m;
}

// ---------------- pairwise max pool over concat [X1|X2|X3] ----------------

__global__ void __launch_bounds__(256) pairmax_kernel(const float* __restrict__ X1,
                                                      const float* __restrict__ X2,
                                                      const float* __restrict__ X3,
                                                      float* __restrict__ P) {
  int i = blockIdx.x * 256 + threadIdx.x;   // over NPTS*96
  int n = i / 96, c = i % 96;
  const float* src = (c < 32) ? X1 : ((c < 64) ? X2 : X3);
  int cc = (c & 31) * 2;
  P[i] = fmaxf(src[(size_t)n * 64 + cc], src[(size_t)n * 64 + cc + 1]);
}

// ---------------- fp32 tiled GEMM: C[N,Nc] = A[N,K] @ B[K,Nc] + bias ----------------

template<bool RELU>
__global__ void __launch_bounds__(256) gemm_kernel(const float* __restrict__ A,
                                                   const float* __restrict__ B,
                                                   const float* __restrict__ bias,
                                                   float* __restrict__ C,
                                                   int K, int Nc) {
  __shared__ float As[16][68];
  __shared__ float Bs[16][68];
  int tid = threadIdx.x;
  int m0 = blockIdx.x * 64, n0 = blockIdx.y * 64;
  int tx = tid & 15, ty = tid >> 4;
  int ar = tid >> 2, ak = (tid & 3) * 4;
  int bk = tid >> 4, bn = (tid & 15) * 4;
  float acc[4][4] = {};
  for (int kt = 0; kt < K; kt += 16) {
    float4 a4 = *reinterpret_cast<const float4*>(&A[(size_t)(m0 + ar) * K + kt + ak]);
    float4 b4 = *reinterpret_cast<const float4*>(&B[(size_t)(kt + bk) * Nc + n0 + bn]);
    __syncthreads();
    As[ak + 0][ar] = a4.x; As[ak + 1][ar] = a4.y; As[ak + 2][ar] = a4.z; As[ak + 3][ar] = a4.w;
    *reinterpret_cast<float4*>(&Bs[bk][bn]) = b4;
    __syncthreads();
    #pragma unroll
    for (int kx = 0; kx < 16; ++kx) {
      float4 av = *reinterpret_cast<const float4*>(&As[kx][ty * 4]);
      float4 bv = *reinterpret_cast<const float4*>(&Bs[kx][tx * 4]);
      float a_[4] = {av.x, av.y, av.z, av.w};
      float b_[4] = {bv.x, bv.y, bv.z, bv.w};
      #pragma unroll
      for (int i = 0; i < 4; ++i)
        #pragma unroll
        for (int j = 0; j < 4; ++j)
          acc[i][j] = fmaf(a_[i], b_[j], acc[i][j]);
    }
  }
  #pragma unroll
  for (int i = 0; i < 4; ++i) {
    int m = m0 + ty * 4 + i;
    float4 r;
    r.x = acc[i][0] + bias[n0 + tx * 4 + 0];
    r.y = acc[i][1] + bias[n0 + tx * 4 + 1];
    r.z = acc[i][2] + bias[n0 + tx * 4 + 2];
    r.w = acc[i][3] + bias[n0 + tx * 4 + 3];
    if (RELU) { r.x = fmaxf(r.x, 0.f); r.y = fmaxf(r.y, 0.f); r.z = fmaxf(r.z, 0.f); r.w = fmaxf(r.w, 0.f); }
    *reinterpret_cast<float4*>(&C[(size_t)m * Nc + n0 + tx * 4]) = r;
  }
}

// ---------------- concat-A GEMM: A = [X1|X2|X3|H], K=1216 ----------------

template<bool RELU>
__global__ void __launch_bounds__(256) gemm_cat_kernel(const float* __restrict__ X1,
                                                       const float* __restrict__ X2,
                                                       const float* __restrict__ X3,
                                                       const float* __restrict__ H,
                                                       const float* __restrict__ B,
                                                       const float* __restrict__ bias,
                                                       float* __restrict__ C, int Nc) {
  const int K = 1216;
  __shared__ float As[16][68];
  __shared__ float Bs[16][68];
  int tid = threadIdx.x;
  int m0 = blockIdx.x * 64, n0 = blockIdx.y * 64;
  int tx = tid & 15, ty = tid >> 4;
  int ar = tid >> 2, ak = (tid & 3) * 4;
  int bk = tid >> 4, bn = (tid & 15) * 4;
  float acc[4][4] = {};
  for (int kt = 0; kt < K; kt += 16) {
    const float* src; int ld, ko;
    if (kt < 64)       { src = X1; ld = 64;   ko = kt; }
    else if (kt < 128) { src = X2; ld = 64;   ko = kt - 64; }
    else if (kt < 192) { src = X3; ld = 64;   ko = kt - 128; }
    else               { src = H;  ld = 1024; ko = kt - 192; }
    float4 a4 = *reinterpret_cast<const float4*>(&src[(size_t)(m0 + ar) * ld + ko + ak]);
    float4 b4 = *reinterpret_cast<const float4*>(&B[(size_t)(kt + bk) * Nc + n0 + bn]);
    __syncthreads();
    As[ak + 0][ar] = a4.x; As[ak + 1][ar] = a4.y; As[ak + 2][ar] = a4.z; As[ak + 3][ar] = a4.w;
    *reinterpret_cast<float4*>(&Bs[bk][bn]) = b4;
    __syncthreads();
    #pragma unroll
    for (int kx = 0; kx < 16; ++kx) {
      float4 av = *reinterpret_cast<const float4*>(&As[kx][ty * 4]);
      float4 bv = *reinterpret_cast<const float4*>(&Bs[kx][tx * 4]);
      float a_[4] = {av.x, av.y, av.z, av.w};
      float b_[4] = {bv.x, bv.y, bv.z, bv.w};
      #pragma unroll
      for (int i = 0; i < 4; ++i)
        #pragma unroll
        for (int j = 0; j < 4; ++j)
          acc[i][j] = fmaf(a_[i], b_[j], acc[i][j]);
    }
  }
  #pragma unroll
  for (int i = 0; i < 4; ++i) {
    int m = m0 + ty * 4 + i;
    float4 r;
    r.x = acc[i][0] + bias[n0 + tx * 4 + 0];
    r.y = acc[i][1] + bias[n0 + tx * 4 + 1];
    r.z = acc[i][2] + bias[n0 + tx * 4 + 2];
    r.w = acc[i][3] + bias[n0 + tx * 4 + 3];
    if (RELU) { r.x = fmaxf(r.x, 0.f); r.y = fmaxf(r.y, 0.f); r.z = fmaxf(r.z, 0.f); r.w = fmaxf(r.w, 0.f); }
    *reinterpret_cast<float4*>(&C[(size_t)m * Nc + n0 + tx * 4]) = r;
  }
}

// ---------------- final [128 -> 3] ----------------

__global__ void __launch_bounds__(256) final3_kernel(const float* __restrict__ Z,
                                                     const float* __restrict__ W,
                                                     const float* __restrict__ b,
                                                     float* __restrict__ out) {
  int n = blockIdx.x * 256 + threadIdx.x;
  float a0 = b[0], a1 = b[1], a2 = b[2];
  #pragma unroll 4
  for (int k = 0; k < 128; ++k) {
    float z = Z[(size_t)n * 128 + k];
    a0 = fmaf(z, W[k * 3 + 0], a0);
    a1 = fmaf(z, W[k * 3 + 1], a1);
    a2 = fmaf(z, W[k * 3 + 2], a2);
  }
  out[n * 3 + 0] = a0;
  out[n * 3 + 1] = a1;
  out[n * 3 + 2] = a2;
}

// ---------------- launch ----------------

extern "C" void kernel_launch(void* const* d_in, const int* in_sizes, int n_in,
                              void* d_out, int out_size, void* d_ws, size_t ws_size,
                              hipStream_t stream) {
  const float* X   = (const float*)d_in[0];
  const float* w1  = (const float*)d_in[1];
  const float* b1  = (const float*)d_in[2];
  const float* w2  = (const float*)d_in[3];
  const float* b2  = (const float*)d_in[4];
  const float* w3  = (const float*)d_in[5];
  const float* b3  = (const float*)d_in[6];
  const float* wc1 = (const float*)d_in[7];
  const float* bc1 = (const float*)d_in[8];
  const float* wc2 = (const float*)d_in[9];
  const float* bc2 = (const float*)d_in[10];
  const float* wc3 = (const float*)d_in[11];
  const float* bc3 = (const float*)d_in[12];
  const float* wc4 = (const float*)d_in[13];
  const float* bc4 = (const float*)d_in[14];
  float* out = (float*)d_out;

  char* ws = (char*)d_ws;
  size_t off = 0;
  auto alloc = [&](size_t bytes) -> void* {
    void* p = ws + off;
    off += (bytes + 255) & ~(size_t)255;
    return p;
  };
  float* sqb = (float*)alloc((size_t)NPTS * 4);
  float* Y   = (float*)alloc((size_t)NPTS * 64 * 4);
  float* X1  = (float*)alloc((size_t)NPTS * 64 * 4);
  float* X2  = (float*)alloc((size_t)NPTS * 64 * 4);
  float* X3  = (float*)alloc((size_t)NPTS * 64 * 4);
  float* Hb  = (float*)alloc((size_t)NPTS * 1024 * 4);          // 67 MB
  unsigned long long* part = (unsigned long long*)Hb;           // aliases H (dead before H written): <=10.5 MB
  float* Z1  = (float*)alloc((size_t)NPTS * 256 * 4);           // 16.8 MB
  int*   idx = (int*)Z1;                                        // aliases Z1 (dead before Z1 written)
  float* Z2  = (float*)alloc((size_t)NPTS * 256 * 4);
  float* P   = (float*)Z2;                                      // aliases Z2 (dead before Z2 written)
  float* Z3  = (float*)alloc((size_t)NPTS * 128 * 4);
  (void)ws_size; (void)in_sizes; (void)n_in; (void)out_size;

  dim3 b256(256);
  const int NQB = NPTS / 64;   // 256 query-blocks for knn6

  // Block 1 (D=9)
  rowsq_kernel<9><<<NPTS / 256, b256, 0, stream>>>(X, sqb);
  knn6_kernel<9, JC9, (NPTS / JC9) / 128><<<NQB * JC9, b256, 0, stream>>>(X, sqb, part);
  merge_kernel<JC9><<<NPTS / 256, b256, 0, stream>>>(part, idx);
  linear_kernel<9><<<NPTS / 4, b256, 0, stream>>>(X, w1, b1, Y);
  gathermax_kernel<<<NPTS / 4, b256, 0, stream>>>(Y, idx, X1);

  // Block 2 (D=64)
  rowsq_kernel<64><<<NPTS / 256, b256, 0, stream>>>(X1, sqb);
  knn6_kernel<64, JC64, (NPTS / JC64) / 128><<<NQB * JC64, b256, 0, stream>>>(X1, sqb, part);
  merge_kernel<JC64><<<NPTS / 256, b256, 0, stream>>>(part, idx);
  linear_kernel<64><<<NPTS / 4, b256, 0, stream>>>(X1, w2, b2, Y);
  gathermax_kernel<<<NPTS / 4, b256, 0, stream>>>(Y, idx, X2);

  // Block 3 (D=64)
  rowsq_kernel<64><<<NPTS / 256, b256, 0, stream>>>(X2, sqb);
  knn6_kernel<64, JC64, (NPTS / JC64) / 128><<<NQB * JC64, b256, 0, stream>>>(X2, sqb, part);
  merge_kernel<JC64><<<NPTS / 256, b256, 0, stream>>>(part, idx);
  linear_kernel<64><<<NPTS / 4, b256, 0, stream>>>(X2, w2, b2, Y);
  gathermax_kernel<<<NPTS / 4, b256, 0, stream>>>(Y, idx, X3);

  // Head
  pairmax_kernel<<<(NPTS * 96) / 256, b256, 0, stream>>>(X1, X2, X3, P);
  gemm_kernel<false><<<dim3(NPTS / 64, 1024 / 64), b256, 0, stream>>>(P, w3, b3, Hb, 96, 1024);
  gemm_cat_kernel<true><<<dim3(NPTS / 64, 256 / 64), b256, 0, stream>>>(X1, X2, X3, Hb, wc1, bc1, Z1, 256);
  gemm_kernel<true><<<dim3(NPTS / 64, 256 / 64), b256, 0, stream>>>(Z1, wc2, bc2, Z2, 256, 256);
  gemm_kernel<true><<<dim3(NPTS / 64, 128 / 64), b256, 0, stream>>>(Z2, wc3, bc3, Z3, 256, 128);
  final3_kernel<<<NPTS / 256, b256, 0, stream>>>(Z3, wc4, bc4, out);
}